// Round 9
// baseline (752.630 us; speedup 1.0000x reference)
//
#include <hip/hip_runtime.h>

// GraphFeatureTokenizer: B=8, HID=768, K=32, TOK=4, MAXLEN=15360
// Outputs concatenated flat (float32): feature [8,15360,768], mask [8,15360], index [8,15360,2]
//
// R6: occupancy lever. R5 post-mortem: compiler pinned VGPR at 64 and
// loop-interchanged away the 16-deep load batch (null result, treatment
// never applied). Wall 296us vs overlap floor ~156us; Occupancy 39%
// (~4 WGs/CU) despite resources allowing ~32 waves/CU -> WG-count cap
// hypothesis. Fix: 2 independent 16-token tiles per 384-thread block
// (two 192-thread halves, per-half code identical to known-good R2).
// Same waves per WG-count -> 2x waves/CU if cap is WG count.

constexpr int BGRAPH = 8;
constexpr int HID    = 768;
constexpr int MAXLEN = 15360;
constexpr int TB     = 16;    // tokens per half-tile
constexpr int HALFT  = 192;   // threads per half: 192 * float4 = 768 cols
constexpr int BLOCK  = 384;   // 2 halves
constexpr int TBB    = 32;    // tokens per block (2 * TB)

typedef float nfloat4 __attribute__((ext_vector_type(4)));

__device__ __forceinline__ void st_nt4(float4* p, float4 v) {
    nfloat4 nv;
    nv.x = v.x; nv.y = v.y; nv.z = v.z; nv.w = v.w;
    __builtin_nontemporal_store(nv, (nfloat4*)p);
}
__device__ __forceinline__ void st_nt1(float* p, float v) {
    __builtin_nontemporal_store(v, p);
}

__global__ __launch_bounds__(BLOCK)
void gft_kernel(const float* __restrict__ embedW,   // [50257,768]
                const float* __restrict__ lapW,     // [64,768]
                const float* __restrict__ orderW,   // [2,768]
                const float* __restrict__ eig,      // [N,32]
                const int*   __restrict__ node_data,// [N,4]
                const int*   __restrict__ edge_data,// [E,4]
                const int*   __restrict__ edge_index,// [2,E]
                const int*   __restrict__ node_num, // [8]
                const int*   __restrict__ edge_num, // [8]
                int E,
                float* __restrict__ outF,
                float* __restrict__ outM,
                float* __restrict__ outI)
{
    const int b    = blockIdx.y;
    const int half = threadIdx.x / HALFT;   // 0 or 1 (wave-uniform: 3 waves per half)
    const int tid  = threadIdx.x % HALFT;
    const int t0   = blockIdx.x * TBB + half * TB;

    // prefix sums over the 8 graphs (uniform scalar loads)
    int ns = 0, es = 0, nn = 0, en = 0;
    #pragma unroll
    for (int g = 0; g < BGRAPH; ++g) {
        int nv = node_num[g], ev = edge_num[g];
        if (g < b)  { ns += nv; es += ev; }
        if (g == b) { nn = nv;  en = ev; }
    }
    const int seq = nn + en;

    float* rowF = outF + ((size_t)b * MAXLEN + t0) * HID;
    const float4 z4 = make_float4(0.f, 0.f, 0.f, 0.f);

    if (blockIdx.x * TBB >= seq) {
        // whole block is padding (both halves): zero feature, mask=1, index=0.
        // No barriers crossed on this path.
        #pragma unroll
        for (int tok = 0; tok < TB; ++tok) {
            st_nt4((float4*)(rowF + (size_t)tok * HID) + tid, z4);
        }
        if (tid < TB) {
            int t = t0 + tid;
            st_nt1(&outM[b * MAXLEN + t], 1.0f);
            st_nt1(&outI[((size_t)b * MAXLEN + t) * 2 + 0], 0.f);
            st_nt1(&outI[((size_t)b * MAXLEN + t) * 2 + 1], 0.f);
        }
        return;
    }

    __shared__ float sh_eig[2][64][TB];   // [half][j][tok]
    __shared__ int   sh_ids[2][TB][4];
    __shared__ int   sh_i0[2][TB], sh_i1[2][TB], sh_gA[2][TB], sh_gB[2][TB];

    // ---- phase 0: token metadata (one thread per token, per half) ----
    if (tid < TB) {
        int t = t0 + tid;
        int i0 = 0, i1 = 0, gA = -1, gB = -1;
        int id0 = 0, id1 = 0, id2 = 0, id3 = 0;
        if (t < seq) {
            if (t < nn) {               // node token
                int g = ns + t;
                i0 = t; i1 = t; gA = g; gB = g;
                id0 = node_data[g * 4 + 0];
                id1 = node_data[g * 4 + 1];
                id2 = node_data[g * 4 + 2];
                id3 = node_data[g * 4 + 3];
            } else {                    // edge token
                int ge = es + (t - nn);
                i0 = edge_index[ge];
                i1 = edge_index[E + ge];
                gA = ns + i0; gB = ns + i1;
                id0 = edge_data[ge * 4 + 0];
                id1 = edge_data[ge * 4 + 1];
                id2 = edge_data[ge * 4 + 2];
                id3 = edge_data[ge * 4 + 3];
            }
        }
        sh_i0[half][tid] = i0; sh_i1[half][tid] = i1;
        sh_gA[half][tid] = gA; sh_gB[half][tid] = gB;
        sh_ids[half][tid][0] = id0; sh_ids[half][tid][1] = id1;
        sh_ids[half][tid][2] = id2; sh_ids[half][tid][3] = id3;
    }
    __syncthreads();

    // ---- phase 1: stage eig pairs into LDS [j][tok] (first 128 threads of each half) ----
    if (tid < 128) {
        int tok   = tid >> 3;           // 0..15
        int jbase = (tid & 7) * 8;      // 0..56
        int gA = sh_gA[half][tok], gB = sh_gB[half][tok];
        #pragma unroll
        for (int jj = 0; jj < 8; ++jj) {
            int j = jbase + jj;
            float v = 0.f;
            if (j < 32) { if (gA >= 0) v = eig[(size_t)gA * 32 + j]; }
            else        { if (gB >= 0) v = eig[(size_t)gB * 32 + (j - 32)]; }
            sh_eig[half][j][tok] = v;
        }
    }
    __syncthreads();

    // ---- phase 2: lap projection. acc[tok] = float4 over this thread's col group ----
    // (per-half code identical to the 296us R2 version -- do not disturb)
    float4 acc[TB];
    #pragma unroll
    for (int i = 0; i < TB; ++i) acc[i] = z4;

    for (int j = 0; j < 64; ++j) {
        float4 w = ((const float4*)(lapW + j * HID))[tid];
        const float4* ev = (const float4*)(&sh_eig[half][j][0]);
        #pragma unroll
        for (int q = 0; q < TB / 4; ++q) {
            float4 e4 = ev[q];
            acc[q*4+0].x += e4.x * w.x; acc[q*4+0].y += e4.x * w.y;
            acc[q*4+0].z += e4.x * w.z; acc[q*4+0].w += e4.x * w.w;
            acc[q*4+1].x += e4.y * w.x; acc[q*4+1].y += e4.y * w.y;
            acc[q*4+1].z += e4.y * w.z; acc[q*4+1].w += e4.y * w.w;
            acc[q*4+2].x += e4.z * w.x; acc[q*4+2].y += e4.z * w.y;
            acc[q*4+2].z += e4.z * w.z; acc[q*4+2].w += e4.z * w.w;
            acc[q*4+3].x += e4.w * w.x; acc[q*4+3].y += e4.w * w.y;
            acc[q*4+3].z += e4.w * w.z; acc[q*4+3].w += e4.w * w.w;
        }
    }

    // ---- phase 3: embedding gather-sum (float4) + order + store ----
    #pragma unroll
    for (int tok = 0; tok < TB; ++tok) {
        int t = t0 + tok;
        float4* dst = (float4*)(rowF + (size_t)tok * HID) + tid;
        if (t >= seq) { st_nt4(dst, z4); continue; }
        float4 s = acc[tok];
        #pragma unroll
        for (int r = 0; r < 4; ++r) {
            float4 e = ((const float4*)(embedW + (size_t)sh_ids[half][tok][r] * HID))[tid];
            s.x += e.x; s.y += e.y; s.z += e.z; s.w += e.w;
        }
        int ord = (sh_i0[half][tok] == sh_i1[half][tok]) ? 1 : 0;
        float4 o = ((const float4*)(orderW + (size_t)ord * HID))[tid];
        s.x += o.x; s.y += o.y; s.z += o.z; s.w += o.w;
        st_nt4(dst, s);
    }

    if (tid < TB) {
        int t = t0 + tid;
        bool pad = (t >= seq);
        st_nt1(&outM[b * MAXLEN + t], pad ? 1.0f : 0.0f);
        st_nt1(&outI[((size_t)b * MAXLEN + t) * 2 + 0], pad ? 0.f : (float)sh_i0[half][tid]);
        st_nt1(&outI[((size_t)b * MAXLEN + t) * 2 + 1], pad ? 0.f : (float)sh_i1[half][tid]);
    }
}

extern "C" void kernel_launch(void* const* d_in, const int* in_sizes, int n_in,
                              void* d_out, int out_size, void* d_ws, size_t ws_size,
                              hipStream_t stream) {
    const float* embedW     = (const float*)d_in[0];
    const float* lapW       = (const float*)d_in[1];
    const float* orderW     = (const float*)d_in[2];
    const float* eig        = (const float*)d_in[3];
    const int*   node_data  = (const int*)d_in[4];
    const int*   edge_data  = (const int*)d_in[5];
    const int*   edge_index = (const int*)d_in[6];
    const int*   node_num   = (const int*)d_in[7];
    const int*   edge_num   = (const int*)d_in[8];
    const int E = in_sizes[6] / 2;

    float* outF = (float*)d_out;
    float* outM = outF + (size_t)BGRAPH * MAXLEN * HID;
    float* outI = outM + (size_t)BGRAPH * MAXLEN;

    dim3 grid(MAXLEN / TBB, BGRAPH);
    gft_kernel<<<grid, BLOCK, 0, stream>>>(embedW, lapW, orderW, eig,
                                           node_data, edge_data, edge_index,
                                           node_num, edge_num, E,
                                           outF, outM, outI);
}

// Round 10
// 679.276 us; speedup vs baseline: 1.1080x; 1.1080x over previous
//
#include <hip/hip_runtime.h>

// GraphFeatureTokenizer: B=8, HID=768, K=32, TOK=4, MAXLEN=15360
// Outputs concatenated flat (float32): feature [8,15360,768], mask [8,15360], index [8,15360,2]
//
// R7: barrier-free per-wave restructure. R6 post-mortem: bigger barrier-
// coupled blocks regressed (occ 39->18%, 1 block/CU); R2<->R6 comparison
// shows per-block phase serialization (all waves stalled at the same
// barrier-drained memory phase) is the limiter, not resident-wave count.
// This version: each of 3 waves is independent (own 256-col slice of all
// 16 tokens, own eig LDS replica, metadata via __shfl from lanes 0-15).
// ZERO __syncthreads -> waves self-stagger, FMA phases of one wave cover
// gather phases of another. Traffic and per-lane FMA count identical to
// the 296us kernel.

constexpr int BGRAPH = 8;
constexpr int HID    = 768;
constexpr int MAXLEN = 15360;
constexpr int TB     = 16;    // tokens per block
constexpr int BLOCK  = 192;   // 3 waves; 192 threads * float4 = 768 cols

typedef float nfloat4 __attribute__((ext_vector_type(4)));

__device__ __forceinline__ void st_nt4(float4* p, float4 v) {
    nfloat4 nv;
    nv.x = v.x; nv.y = v.y; nv.z = v.z; nv.w = v.w;
    __builtin_nontemporal_store(nv, (nfloat4*)p);
}
__device__ __forceinline__ void st_nt1(float* p, float v) {
    __builtin_nontemporal_store(v, p);
}

__global__ __launch_bounds__(BLOCK)
void gft_kernel(const float* __restrict__ embedW,   // [50257,768]
                const float* __restrict__ lapW,     // [64,768]
                const float* __restrict__ orderW,   // [2,768]
                const float* __restrict__ eig,      // [N,32]
                const int*   __restrict__ node_data,// [N,4]
                const int*   __restrict__ edge_data,// [E,4]
                const int*   __restrict__ edge_index,// [2,E]
                const int*   __restrict__ node_num, // [8]
                const int*   __restrict__ edge_num, // [8]
                int E,
                float* __restrict__ outF,
                float* __restrict__ outM,
                float* __restrict__ outI)
{
    const int b    = blockIdx.y;
    const int t0   = blockIdx.x * TB;
    const int tid  = threadIdx.x;
    const int wave = tid >> 6;
    const int lane = tid & 63;

    // prefix sums over the 8 graphs (uniform scalar loads)
    int ns = 0, es = 0, nn = 0, en = 0;
    #pragma unroll
    for (int g = 0; g < BGRAPH; ++g) {
        int nv = node_num[g], ev = edge_num[g];
        if (g < b)  { ns += nv; es += ev; }
        if (g == b) { nn = nv;  en = ev; }
    }
    const int seq = nn + en;

    float* rowF = outF + ((size_t)b * MAXLEN + t0) * HID;
    const float4 z4 = make_float4(0.f, 0.f, 0.f, 0.f);

    if (t0 >= seq) {
        // whole tile is padding: zero feature, mask=1, index=0
        #pragma unroll
        for (int tok = 0; tok < TB; ++tok) {
            st_nt4((float4*)(rowF + (size_t)tok * HID) + tid, z4);
        }
        if (tid < TB) {
            int t = t0 + tid;
            st_nt1(&outM[b * MAXLEN + t], 1.0f);
            st_nt1(&outI[((size_t)b * MAXLEN + t) * 2 + 0], 0.f);
            st_nt1(&outI[((size_t)b * MAXLEN + t) * 2 + 1], 0.f);
        }
        return;
    }

    // per-wave eig replica: exclusive LDS region per wave -> no cross-wave hazard
    __shared__ float sh_eig[3][64][TB];

    // ---- phase 0 (registers, lanes 0..15 of EVERY wave, redundant x3) ----
    int my_i0 = 0, my_i1 = 0, my_gA = -1, my_gB = -1;
    int my_id0 = 0, my_id1 = 0, my_id2 = 0, my_id3 = 0;
    if (lane < TB) {
        int t = t0 + lane;
        if (t < seq) {
            if (t < nn) {               // node token
                int g = ns + t;
                my_i0 = t; my_i1 = t; my_gA = g; my_gB = g;
                my_id0 = node_data[g * 4 + 0];
                my_id1 = node_data[g * 4 + 1];
                my_id2 = node_data[g * 4 + 2];
                my_id3 = node_data[g * 4 + 3];
            } else {                    // edge token
                int ge = es + (t - nn);
                my_i0 = edge_index[ge];
                my_i1 = edge_index[E + ge];
                my_gA = ns + my_i0; my_gB = ns + my_i1;
                my_id0 = edge_data[ge * 4 + 0];
                my_id1 = edge_data[ge * 4 + 1];
                my_id2 = edge_data[ge * 4 + 2];
                my_id3 = edge_data[ge * 4 + 3];
            }
        }
    }

    // mask/index outputs: wave 0, lanes 0..15 use their own registers
    if (tid < TB) {
        int t = t0 + tid;
        bool pad = (t >= seq);
        st_nt1(&outM[b * MAXLEN + t], pad ? 1.0f : 0.0f);
        st_nt1(&outI[((size_t)b * MAXLEN + t) * 2 + 0], pad ? 0.f : (float)my_i0);
        st_nt1(&outI[((size_t)b * MAXLEN + t) * 2 + 1], pad ? 0.f : (float)my_i1);
    }

    // ---- phase 1: stage this wave's eig replica [j][tok] (wave-local) ----
    {
        int tok  = lane & 15;           // 0..15
        int jseg = lane >> 4;           // 0..3 -> j in [jseg*16, jseg*16+16)
        int gA = __shfl(my_gA, tok);
        int gB = __shfl(my_gB, tok);
        #pragma unroll
        for (int jj = 0; jj < 16; ++jj) {
            int j = jseg * 16 + jj;
            float v = 0.f;
            if (j < 32) { if (gA >= 0) v = eig[(size_t)gA * 32 + j]; }
            else        { if (gB >= 0) v = eig[(size_t)gB * 32 + (j - 32)]; }
            sh_eig[wave][j][tok] = v;
        }
    }
    // same-wave LDS RAW: hardware lgkmcnt ordering + keep compiler from
    // migrating reads above the writes
    __builtin_amdgcn_wave_barrier();

    // ---- phase 2: lap projection. acc[tok] = float4 over this thread's col group ----
    // (identical FMA structure to the 296us kernel; ev reads are wave-local broadcasts)
    float4 acc[TB];
    #pragma unroll
    for (int i = 0; i < TB; ++i) acc[i] = z4;

    for (int j = 0; j < 64; ++j) {
        float4 w = ((const float4*)(lapW + j * HID))[tid];
        const float4* ev = (const float4*)(&sh_eig[wave][j][0]);
        #pragma unroll
        for (int q = 0; q < TB / 4; ++q) {
            float4 e4 = ev[q];
            acc[q*4+0].x += e4.x * w.x; acc[q*4+0].y += e4.x * w.y;
            acc[q*4+0].z += e4.x * w.z; acc[q*4+0].w += e4.x * w.w;
            acc[q*4+1].x += e4.y * w.x; acc[q*4+1].y += e4.y * w.y;
            acc[q*4+1].z += e4.y * w.z; acc[q*4+1].w += e4.y * w.w;
            acc[q*4+2].x += e4.z * w.x; acc[q*4+2].y += e4.z * w.y;
            acc[q*4+2].z += e4.z * w.z; acc[q*4+2].w += e4.z * w.w;
            acc[q*4+3].x += e4.w * w.x; acc[q*4+3].y += e4.w * w.y;
            acc[q*4+3].z += e4.w * w.z; acc[q*4+3].w += e4.w * w.w;
        }
    }

    // ---- phase 3: embedding gather-sum + order + store; ids via wave shuffles ----
    #pragma unroll
    for (int tok = 0; tok < TB; ++tok) {
        int t = t0 + tok;                       // wave-uniform
        float4* dst = (float4*)(rowF + (size_t)tok * HID) + tid;
        if (t >= seq) { st_nt4(dst, z4); continue; }   // uniform branch
        int sid0 = __shfl(my_id0, tok);
        int sid1 = __shfl(my_id1, tok);
        int sid2 = __shfl(my_id2, tok);
        int sid3 = __shfl(my_id3, tok);
        int si0  = __shfl(my_i0, tok);
        int si1  = __shfl(my_i1, tok);
        float4 s = acc[tok];
        float4 e0 = ((const float4*)(embedW + (size_t)sid0 * HID))[tid];
        float4 e1 = ((const float4*)(embedW + (size_t)sid1 * HID))[tid];
        float4 e2 = ((const float4*)(embedW + (size_t)sid2 * HID))[tid];
        float4 e3 = ((const float4*)(embedW + (size_t)sid3 * HID))[tid];
        s.x += e0.x + e1.x + e2.x + e3.x;
        s.y += e0.y + e1.y + e2.y + e3.y;
        s.z += e0.z + e1.z + e2.z + e3.z;
        s.w += e0.w + e1.w + e2.w + e3.w;
        int ord = (si0 == si1) ? 1 : 0;
        float4 o = ((const float4*)(orderW + (size_t)ord * HID))[tid];
        s.x += o.x; s.y += o.y; s.z += o.z; s.w += o.w;
        st_nt4(dst, s);
    }
}

extern "C" void kernel_launch(void* const* d_in, const int* in_sizes, int n_in,
                              void* d_out, int out_size, void* d_ws, size_t ws_size,
                              hipStream_t stream) {
    const float* embedW     = (const float*)d_in[0];
    const float* lapW       = (const float*)d_in[1];
    const float* orderW     = (const float*)d_in[2];
    const float* eig        = (const float*)d_in[3];
    const int*   node_data  = (const int*)d_in[4];
    const int*   edge_data  = (const int*)d_in[5];
    const int*   edge_index = (const int*)d_in[6];
    const int*   node_num   = (const int*)d_in[7];
    const int*   edge_num   = (const int*)d_in[8];
    const int E = in_sizes[6] / 2;

    float* outF = (float*)d_out;
    float* outM = outF + (size_t)BGRAPH * MAXLEN * HID;
    float* outI = outM + (size_t)BGRAPH * MAXLEN;

    dim3 grid(MAXLEN / TB, BGRAPH);
    gft_kernel<<<grid, BLOCK, 0, stream>>>(embedW, lapW, orderW, eig,
                                           node_data, edge_data, edge_index,
                                           node_num, edge_num, E,
                                           outF, outM, outI);
}